// Round 1
// baseline (688.454 us; speedup 1.0000x reference)
//
#include <hip/hip_runtime.h>
#include <math.h>

#define NG 100000
#define ND 50000
#define NTOT 150000
#define DIM 128
#define NE 800000
#define EPSN 1e-12f

#define NBT_D 391  // ceil(ND/128)
#define NBT_G 782  // ceil(NG/128)

#define NBK 586    // ceil(NTOT/256) buckets of 256 dst nodes
#define SCB 128    // scatter blocks
#define EPB 12500  // edges per scatter block = ceil(2*NE/SCB)

typedef __bf16 bf16x8 __attribute__((ext_vector_type(8)));
typedef float f32x4 __attribute__((ext_vector_type(4)));
typedef unsigned int uint32;

__device__ __forceinline__ ushort rne_bf16(float f) {
  uint32 u = __builtin_bit_cast(uint32, f);
  u += 0x7fffu + ((u >> 16) & 1u);
  return (ushort)(u >> 16);
}

// ---------------- bucketed CSR build ----------------
// unified dst space: disease dsts [0,ND), gene dsts [ND,NTOT). bucket = dst>>8.

__global__ void zero_ints(int* __restrict__ p, int n) {
  int i = blockIdx.x * 256 + threadIdx.x;
  if (i < n) p[i] = 0;
}

// Pass A1: per-bucket edge counts (LDS histogram -> few global atomics)
__global__ void bucket_count(const int* __restrict__ dst_g2d, const int* __restrict__ dst_d2g,
                             int* __restrict__ bcnt) {
  __shared__ int h[NBK];
  for (int j = threadIdx.x; j < NBK; j += 256) h[j] = 0;
  __syncthreads();
  int stride = gridDim.x * 256;
  for (int i = blockIdx.x * 256 + threadIdx.x; i < 2 * NE; i += stride) {
    int d = (i < NE) ? dst_g2d[i] : ND + dst_d2g[i - NE];
    atomicAdd(&h[d >> 8], 1);
  }
  __syncthreads();
  for (int j = threadIdx.x; j < NBK; j += 256)
    if (h[j]) atomicAdd(&bcnt[j], h[j]);
}

// Pass A2: exclusive scan of bucket counts; init cursors
__global__ void bucket_scan(const int* __restrict__ bcnt, int* __restrict__ bbase,
                            int* __restrict__ bcur) {
  __shared__ int s[1024];
  int t = threadIdx.x;
  s[t] = (t < NBK) ? bcnt[t] : 0;
  __syncthreads();
  for (int off = 1; off < 1024; off <<= 1) {
    int v = (t >= off) ? s[t - off] : 0;
    __syncthreads();
    s[t] += v;
    __syncthreads();
  }
  if (t < NBK) {
    int e = (t > 0) ? s[t - 1] : 0;
    bbase[t] = e;
    bcur[t] = e;
  }
  if (t == 0) bbase[NBK] = 2 * NE;
}

// Pass A3: scatter (dst,src) pairs into bucket segments.
__global__ void bucket_scatter(const int* __restrict__ src_g2d, const int* __restrict__ dst_g2d,
                               const int* __restrict__ src_d2g, const int* __restrict__ dst_d2g,
                               int* __restrict__ bcur, int2* __restrict__ pairs) {
  __shared__ int h[NBK];
  __shared__ int base[NBK];
  int e0 = blockIdx.x * EPB;
  int e1 = e0 + EPB;
  if (e1 > 2 * NE) e1 = 2 * NE;
  for (int j = threadIdx.x; j < NBK; j += 256) h[j] = 0;
  __syncthreads();
  for (int i = e0 + threadIdx.x; i < e1; i += 256) {
    int d = (i < NE) ? dst_g2d[i] : ND + dst_d2g[i - NE];
    atomicAdd(&h[d >> 8], 1);
  }
  __syncthreads();
  for (int j = threadIdx.x; j < NBK; j += 256) {
    int c = h[j];
    base[j] = c ? atomicAdd(&bcur[j], c) : 0;
    h[j] = 0;  // reuse as local cursor
  }
  __syncthreads();
  for (int i = e0 + threadIdx.x; i < e1; i += 256) {
    int d, s;
    if (i < NE) {
      d = dst_g2d[i];
      s = src_g2d[i];
    } else {
      d = ND + dst_d2g[i - NE];
      s = src_d2g[i - NE];
    }
    int bkt = d >> 8;
    int p = base[bkt] + atomicAdd(&h[bkt], 1);
    pairs[p] = make_int2(d, s);
  }
}

// Pass B: one block per bucket -> off[] + csr placement
__global__ void bucket_to_csr(const int* __restrict__ bbase, const int2* __restrict__ pairs,
                              int* __restrict__ off, int* __restrict__ csr) {
  __shared__ int cnt[256];
  __shared__ int ss[256];
  int b = blockIdx.x, t = threadIdx.x;
  int n0 = b << 8;
  int s0 = bbase[b], s1 = bbase[b + 1];
  cnt[t] = 0;
  __syncthreads();
  for (int i = s0 + t; i < s1; i += 256) atomicAdd(&cnt[pairs[i].x - n0], 1);
  __syncthreads();
  int x = cnt[t];
  ss[t] = x;
  __syncthreads();
  for (int o = 1; o < 256; o <<= 1) {
    int y = (t >= o) ? ss[t - o] : 0;
    __syncthreads();
    ss[t] += y;
    __syncthreads();
  }
  int abs0 = s0 + ss[t] - x;
  int node = n0 + t;
  if (node < NTOT) off[node] = abs0;
  if (node == NTOT - 1) off[NTOT] = 2 * NE;
  __syncthreads();
  cnt[t] = abs0;  // absolute cursor
  __syncthreads();
  for (int i = s0 + t; i < s1; i += 256) {
    int2 e = pairs[i];
    int p = atomicAdd(&cnt[e.x - n0], 1);
    csr[p] = e.y;
  }
}

// ---------------- fp32 -> bf16 table convert (RNE), both tables in one launch ------------

__global__ void to_bf16_all(const float* __restrict__ xg, const float* __restrict__ xd,
                            ushort* __restrict__ yg, ushort* __restrict__ yd) {
  int i = blockIdx.x * 256 + threadIdx.x;
  if (i >= NTOT * 16) return;
  const float* x;
  ushort* y;
  int j;
  if (i < NG * 16) {
    x = xg; y = yg; j = i;
  } else {
    x = xd; y = yd; j = i - NG * 16;
  }
  const float4* px = (const float4*)x;
  float4 a = px[2 * j], b = px[2 * j + 1];
  float v[8] = {a.x, a.y, a.z, a.w, b.x, b.y, b.z, b.w};
  uint32 u[4];
#pragma unroll
  for (int k = 0; k < 4; k++)
    u[k] = (uint32)rne_bf16(v[2 * k]) | ((uint32)rne_bf16(v[2 * k + 1]) << 16);
  ((int4*)y)[j] = make_int4((int)u[0], (int)u[1], (int)u[2], (int)u[3]);
}

// ---------------- W pre-split: fp32 -> bf16 hi (trunc) + bf16 lo (residual) --------------

__global__ void split_w(const float* __restrict__ Wl, const float* __restrict__ Wr,
                        ushort* __restrict__ WlH, ushort* __restrict__ WlL,
                        ushort* __restrict__ WrH, ushort* __restrict__ WrL) {
  int i = blockIdx.x * 256 + threadIdx.x;
  if (i >= 4 * 128 * 128) return;
  {
    float a = Wl[i];
    uint32 u = __builtin_bit_cast(uint32, a);
    float hf = __builtin_bit_cast(float, u & 0xffff0000u);
    WlH[i] = (ushort)(u >> 16);
    WlL[i] = (ushort)(__builtin_bit_cast(uint32, a - hf) >> 16);
  }
  {
    float a = Wr[i];
    uint32 u = __builtin_bit_cast(uint32, a);
    float hf = __builtin_bit_cast(float, u & 0xffff0000u);
    WrH[i] = (ushort)(u >> 16);
    WrL[i] = (ushort)(__builtin_bit_cast(uint32, a - hf) >> 16);
  }
}

// ---------------- fused gather-mean + MFMA SAGE update -----------------------------------

__device__ __forceinline__ void acc8(float* a, int4 u) {
  uint32 w;
  w = (uint32)u.x;
  a[0] += __builtin_bit_cast(float, w << 16);
  a[1] += __builtin_bit_cast(float, w & 0xffff0000u);
  w = (uint32)u.y;
  a[2] += __builtin_bit_cast(float, w << 16);
  a[3] += __builtin_bit_cast(float, w & 0xffff0000u);
  w = (uint32)u.z;
  a[4] += __builtin_bit_cast(float, w << 16);
  a[5] += __builtin_bit_cast(float, w & 0xffff0000u);
  w = (uint32)u.w;
  a[6] += __builtin_bit_cast(float, w << 16);
  a[7] += __builtin_bit_cast(float, w & 0xffff0000u);
}

// LDS: sA = [4 ks][128][40] bf16 gathered A-tile (40960B); during ph1 its first
// 20480B are reused as [2 planes][128][40] X hi/lo staging. sW = [2 planes][128][40].
__launch_bounds__(256)
__global__ void sage_fused(const ushort* __restrict__ tab_g, const ushort* __restrict__ tab_d,
                           const float* __restrict__ xd, const float* __restrict__ xg,
                           const int* __restrict__ off, const int* __restrict__ csr,
                           const ushort* __restrict__ WlH, const ushort* __restrict__ WlL,
                           const ushort* __restrict__ WrH, const ushort* __restrict__ WrL,
                           const float* __restrict__ bias_all, float* __restrict__ outd,
                           float* __restrict__ outg, ushort* __restrict__ xbf_d,
                           ushort* __restrict__ xbf_g, int layer, int relu, int write_bf) {
  __shared__ __align__(16) char smem[61440];
  ushort* sA = (ushort*)smem;            // 40960B
  ushort* sW = (ushort*)(smem + 40960);  // 20480B

  int b = blockIdx.x;
  const float* X;
  float* O;
  ushort* OBF;
  const ushort* xs;
  int n, set, r0g, cbase;
  if (b < NBT_D) {
    X = xd; O = outd; OBF = xbf_d; xs = tab_g; n = ND; set = layer * 2; r0g = b * 128;
    cbase = 0;
  } else {
    X = xg; O = outg; OBF = xbf_g; xs = tab_d; n = NG; set = layer * 2 + 1;
    r0g = (b - NBT_D) * 128; cbase = ND;
  }
  const ushort* WH[2] = {WlH + set * 16384, WrH + set * 16384};
  const ushort* WL[2] = {WlL + set * 16384, WrL + set * 16384};
  const float* bias = bias_all + set * 128;

  int tid = threadIdx.x;

  // ---- gather-mean phase: 16 lanes per node, 16 groups, 8 node-rounds ----
  {
    int grp = tid >> 4, l16 = tid & 15;
    const int4* xs4 = (const int4*)xs;
    for (int t = 0; t < 8; t++) {
      int lr = t * 16 + grp;  // 0..127 local row
      int rg = r0g + lr;
      if (rg >= n) rg = n - 1;
      int u = cbase + rg;
      int e0 = off[u], e1 = off[u + 1];
      float a[8] = {0.f, 0.f, 0.f, 0.f, 0.f, 0.f, 0.f, 0.f};
      float c[8] = {0.f, 0.f, 0.f, 0.f, 0.f, 0.f, 0.f, 0.f};
      int e = e0;
      for (; e + 1 < e1; e += 2) {
        int s0 = csr[e], s1 = csr[e + 1];
        int4 v0 = xs4[(size_t)s0 * 16 + l16];
        int4 v1 = xs4[(size_t)s1 * 16 + l16];
        acc8(a, v0);
        acc8(c, v1);
      }
      if (e < e1) acc8(a, xs4[(size_t)csr[e] * 16 + l16]);
      int deg = e1 - e0;
      float inv = (deg > 0) ? 1.f / (float)deg : 0.f;
      uint32 up[4];
#pragma unroll
      for (int j = 0; j < 4; j++)
        up[j] = (uint32)rne_bf16((a[2 * j] + c[2 * j]) * inv) |
                ((uint32)rne_bf16((a[2 * j + 1] + c[2 * j + 1]) * inv) << 16);
      int ks = l16 >> 2, wp = l16 & 3;
      *(int4*)&sA[ks * 5120 + lr * 40 + wp * 8] =
          make_int4((int)up[0], (int)up[1], (int)up[2], (int)up[3]);
    }
  }

  // ---- GEMM phase ----
  int wave = tid >> 6, lane = tid & 63;
  int m = lane & 15, q = lane >> 4;
  int arow0 = wave * 32 + m;
  int arow1 = arow0 + 16;

  f32x4 acc[2][8];
#pragma unroll
  for (int mt = 0; mt < 2; mt++)
#pragma unroll
    for (int nt = 0; nt < 8; nt++) acc[mt][nt] = (f32x4)0.f;

  auto loadW = [&](int ph, int ks, int4* dst) {
#pragma unroll
    for (int i = 0; i < 4; i++) {
      int u = tid + i * 256;
      int pl = u >> 9, idx = u & 511, wn = idx >> 2, wp2 = idx & 3;
      const ushort* base = pl ? WL[ph] : WH[ph];
      dst[i] = *(const int4*)&base[wn * 128 + ks * 32 + wp2 * 8];
    }
  };
  auto storeW = [&](const int4* src) {
#pragma unroll
    for (int i = 0; i < 4; i++) {
      int u = tid + i * 256;
      int pl = u >> 9, idx = u & 511, wn = idx >> 2, wp2 = idx & 3;
      *(int4*)&sW[pl * 5120 + wn * 40 + wp2 * 8] = src[i];
    }
  };
  auto loadX = [&](int ks, float4* dst) {
#pragma unroll
    for (int i = 0; i < 4; i++) {
      int u = tid + i * 256;
      int xn = u >> 3, xp = u & 7;
      int rg = r0g + xn;
      if (rg >= n) rg = n - 1;
      dst[i] = *(const float4*)&X[(size_t)rg * DIM + ks * 32 + xp * 4];
    }
  };
  auto storeX = [&](const float4* src) {
#pragma unroll
    for (int i = 0; i < 4; i++) {
      int u = tid + i * 256;
      int xn = u >> 3, xp = u & 7;
      float v[4] = {src[i].x, src[i].y, src[i].z, src[i].w};
      ushort h[4], l[4];
#pragma unroll
      for (int j = 0; j < 4; j++) {
        uint32 uu = __builtin_bit_cast(uint32, v[j]);
        h[j] = (ushort)(uu >> 16);
        float hf = __builtin_bit_cast(float, uu & 0xffff0000u);
        l[j] = (ushort)(__builtin_bit_cast(uint32, v[j] - hf) >> 16);
      }
      int2 hp = make_int2((int)((uint32)h[0] | ((uint32)h[1] << 16)),
                          (int)((uint32)h[2] | ((uint32)h[3] << 16)));
      int2 lp = make_int2((int)((uint32)l[0] | ((uint32)l[1] << 16)),
                          (int)((uint32)l[2] | ((uint32)l[3] << 16)));
      *(int2*)&sA[xn * 40 + xp * 4] = hp;
      *(int2*)&sA[5120 + xn * 40 + xp * 4] = lp;
    }
  };

  // ---- ph0: neighbors (A resident in sA; only W staged; prefetch next-ks W) ----
  {
    int4 wv[4];
    loadW(0, 0, wv);
#pragma unroll
    for (int ks = 0; ks < 4; ks++) {
      __syncthreads();  // prev MFMA done (ks=0: gather writes done)
      storeW(wv);
      int4 wvn[4];
      if (ks < 3) loadW(0, ks + 1, wvn);
      __syncthreads();
      bf16x8 a0 = __builtin_bit_cast(bf16x8, *(const int4*)&sA[ks * 5120 + arow0 * 40 + q * 8]);
      bf16x8 a1 = __builtin_bit_cast(bf16x8, *(const int4*)&sA[ks * 5120 + arow1 * 40 + q * 8]);
#pragma unroll
      for (int nt = 0; nt < 8; nt++) {
        int nn = nt * 16 + m;
        bf16x8 bh = __builtin_bit_cast(bf16x8, *(const int4*)&sW[nn * 40 + q * 8]);
        bf16x8 bl = __builtin_bit_cast(bf16x8, *(const int4*)&sW[5120 + nn * 40 + q * 8]);
        acc[0][nt] = __builtin_amdgcn_mfma_f32_16x16x32_bf16(a0, bh, acc[0][nt], 0, 0, 0);
        acc[1][nt] = __builtin_amdgcn_mfma_f32_16x16x32_bf16(a1, bh, acc[1][nt], 0, 0, 0);
        acc[0][nt] = __builtin_amdgcn_mfma_f32_16x16x32_bf16(a0, bl, acc[0][nt], 0, 0, 0);
        acc[1][nt] = __builtin_amdgcn_mfma_f32_16x16x32_bf16(a1, bl, acc[1][nt], 0, 0, 0);
      }
      if (ks < 3) {
#pragma unroll
        for (int i = 0; i < 4; i++) wv[i] = wvn[i];
      }
    }
  }

  // ---- ph1: root X (hi/lo staged into sA's first 20KB; prefetch next-ks W+X) ----
  {
    int4 wv[4];
    float4 xv[4];
    loadW(1, 0, wv);
    loadX(0, xv);
#pragma unroll
    for (int ks = 0; ks < 4; ks++) {
      __syncthreads();  // ph0 last MFMA (reads sA/sW) done before overwrite
      storeW(wv);
      storeX(xv);
      int4 wvn[4];
      float4 xvn[4];
      if (ks < 3) {
        loadW(1, ks + 1, wvn);
        loadX(ks + 1, xvn);
      }
      __syncthreads();
      bf16x8 ah0 = __builtin_bit_cast(bf16x8, *(const int4*)&sA[arow0 * 40 + q * 8]);
      bf16x8 ah1 = __builtin_bit_cast(bf16x8, *(const int4*)&sA[arow1 * 40 + q * 8]);
      bf16x8 al0 = __builtin_bit_cast(bf16x8, *(const int4*)&sA[5120 + arow0 * 40 + q * 8]);
      bf16x8 al1 = __builtin_bit_cast(bf16x8, *(const int4*)&sA[5120 + arow1 * 40 + q * 8]);
#pragma unroll
      for (int nt = 0; nt < 8; nt++) {
        int nn = nt * 16 + m;
        bf16x8 bh = __builtin_bit_cast(bf16x8, *(const int4*)&sW[nn * 40 + q * 8]);
        bf16x8 bl = __builtin_bit_cast(bf16x8, *(const int4*)&sW[5120 + nn * 40 + q * 8]);
        acc[0][nt] = __builtin_amdgcn_mfma_f32_16x16x32_bf16(ah0, bh, acc[0][nt], 0, 0, 0);
        acc[1][nt] = __builtin_amdgcn_mfma_f32_16x16x32_bf16(ah1, bh, acc[1][nt], 0, 0, 0);
        acc[0][nt] = __builtin_amdgcn_mfma_f32_16x16x32_bf16(ah0, bl, acc[0][nt], 0, 0, 0);
        acc[1][nt] = __builtin_amdgcn_mfma_f32_16x16x32_bf16(ah1, bl, acc[1][nt], 0, 0, 0);
        acc[0][nt] = __builtin_amdgcn_mfma_f32_16x16x32_bf16(al0, bh, acc[0][nt], 0, 0, 0);
        acc[1][nt] = __builtin_amdgcn_mfma_f32_16x16x32_bf16(al1, bh, acc[1][nt], 0, 0, 0);
      }
      if (ks < 3) {
#pragma unroll
        for (int i = 0; i < 4; i++) {
          wv[i] = wvn[i];
          xv[i] = xvn[i];
        }
      }
    }
  }
  __syncthreads();

  // ---- epilogue: bias, relu, L2-normalize, skipsum, store (+ optional bf16 copy) ----
  float bb[8];
#pragma unroll
  for (int nt = 0; nt < 8; nt++) bb[nt] = bias[nt * 16 + m];

  const int S = 132;
  float* wbuf = (float*)smem + wave * (16 * S);

  int half = lane >> 5;
  int c4 = (lane & 31) * 4;

#pragma unroll
  for (int mt = 0; mt < 2; mt++) {
#pragma unroll
    for (int reg = 0; reg < 4; reg++) {
      float h[8];
      float ss = 0.f;
#pragma unroll
      for (int nt = 0; nt < 8; nt++) {
        float v = acc[mt][nt][reg] + bb[nt];
        if (relu) v = fmaxf(v, 0.f);
        h[nt] = v;
        ss += v * v;
      }
      ss += __shfl_xor(ss, 1);
      ss += __shfl_xor(ss, 2);
      ss += __shfl_xor(ss, 4);
      ss += __shfl_xor(ss, 8);
      float inv = 1.f / fmaxf(sqrtf(ss), EPSN);
      int rrel = q * 4 + reg;
#pragma unroll
      for (int nt = 0; nt < 8; nt++) wbuf[rrel * S + nt * 16 + m] = h[nt] * inv;
    }
#pragma unroll
    for (int i = 0; i < 8; i++) {
      int rrel = i * 2 + half;
      int R = r0g + wave * 32 + mt * 16 + rrel;
      if (R < n) {
        f32x4 hv = *(const f32x4*)&wbuf[rrel * S + c4];
        float4 xr = *(const float4*)&X[(size_t)R * DIM + c4];
        float4 o;
        o.x = hv[0] + xr.x;
        o.y = hv[1] + xr.y;
        o.z = hv[2] + xr.z;
        o.w = hv[3] + xr.w;
        *(float4*)&O[(size_t)R * DIM + c4] = o;
        if (write_bf) {
          int2 pk = make_int2((int)((uint32)rne_bf16(o.x) | ((uint32)rne_bf16(o.y) << 16)),
                              (int)((uint32)rne_bf16(o.z) | ((uint32)rne_bf16(o.w) << 16)));
          *(int2*)&OBF[(size_t)R * DIM + c4] = pk;
        }
      }
    }
  }
}

// ---------------- launch ----------------

extern "C" void kernel_launch(void* const* d_in, const int* in_sizes, int n_in,
                              void* d_out, int out_size, void* d_ws, size_t ws_size,
                              hipStream_t stream) {
  const float* xg0 = (const float*)d_in[0];
  const float* xd0 = (const float*)d_in[1];
  const float* Wl = (const float*)d_in[2];
  const float* Wr = (const float*)d_in[3];
  const float* bs = (const float*)d_in[4];
  const int* src_g2d = (const int*)d_in[5];
  const int* dst_g2d = (const int*)d_in[6];
  const int* src_d2g = (const int*)d_in[7];
  const int* dst_d2g = (const int*)d_in[8];

  float* out_xg = (float*)d_out;
  float* out_xd = (float*)d_out + (size_t)NG * DIM;

  char* p = (char*)d_ws;
  auto alloc = [&](size_t bytes) -> char* {
    char* q = p;
    p += (bytes + 255) & ~(size_t)255;
    return q;
  };
  int* off = (int*)alloc((NTOT + 1) * 4);
  int* csr = (int*)alloc((size_t)2 * NE * 4);
  int* bcnt = (int*)alloc(NBK * 4);
  int* bbase = (int*)alloc((NBK + 1) * 4);
  int* bcur = (int*)alloc(NBK * 4);
  // big (38.4 MB): pairs (12.8 MB) during CSR build, then the layer-0 bf16 output
  // tables (exactly NTOT*DIM*2 bytes) that layer-1 gathers from.
  char* big = alloc((size_t)NTOT * DIM * 2);
  int2* pairs = (int2*)big;
  ushort* xg_bf2 = (ushort*)big;
  ushort* xd_bf2 = xg_bf2 + (size_t)NG * DIM;
  ushort* xg_bf = (ushort*)alloc((size_t)NG * DIM * 2);
  ushort* xd_bf = (ushort*)alloc((size_t)ND * DIM * 2);
  ushort* WlH = (ushort*)alloc((size_t)4 * 128 * 128 * 2);
  ushort* WlL = (ushort*)alloc((size_t)4 * 128 * 128 * 2);
  ushort* WrH = (ushort*)alloc((size_t)4 * 128 * 128 * 2);
  ushort* WrL = (ushort*)alloc((size_t)4 * 128 * 128 * 2);

  const int TB = 256;

  split_w<<<256, TB, 0, stream>>>(Wl, Wr, WlH, WlL, WrH, WrL);
  to_bf16_all<<<(NTOT * 16 + TB - 1) / TB, TB, 0, stream>>>(xg0, xd0, xg_bf, xd_bf);

  // bucketed CSR build
  zero_ints<<<(NBK + TB - 1) / TB, TB, 0, stream>>>(bcnt, NBK);
  bucket_count<<<256, TB, 0, stream>>>(dst_g2d, dst_d2g, bcnt);
  bucket_scan<<<1, 1024, 0, stream>>>(bcnt, bbase, bcur);
  bucket_scatter<<<SCB, TB, 0, stream>>>(src_g2d, dst_g2d, src_d2g, dst_d2g, bcur, pairs);
  bucket_to_csr<<<NBK, TB, 0, stream>>>(bbase, pairs, off, csr);

  int sageBlocks = NBT_D + NBT_G;  // 1173

  // layer 0 (relu): gather from v1 bf16 tables, write bf16 outputs to v2 tables
  sage_fused<<<sageBlocks, TB, 0, stream>>>(xg_bf, xd_bf, xd0, xg0, off, csr, WlH, WlL, WrH,
                                            WrL, bs, out_xd, out_xg, xd_bf2, xg_bf2, 0, 1, 1);

  // layer 1 (no relu), in-place on d_out; gather from v2 tables
  sage_fused<<<sageBlocks, TB, 0, stream>>>(xg_bf2, xd_bf2, out_xd, out_xg, off, csr, WlH, WlL,
                                            WrH, WrL, bs, out_xd, out_xg, xd_bf, xg_bf, 1, 0, 0);
}

// Round 2
// 620.253 us; speedup vs baseline: 1.1100x; 1.1100x over previous
//
#include <hip/hip_runtime.h>
#include <math.h>

#define NG 100000
#define ND 50000
#define NTOT 150000
#define DIM 128
#define NE 800000
#define EPSN 1e-12f

#define NBT_D 391  // ceil(ND/128)
#define NBT_G 782  // ceil(NG/128)

#define NBK 586    // ceil(NTOT/256) buckets of 256 dst nodes
#define SCB 128    // scatter blocks
#define EPB 12500  // edges per scatter block = ceil(2*NE/SCB)

typedef __bf16 bf16x8 __attribute__((ext_vector_type(8)));
typedef float f32x4 __attribute__((ext_vector_type(4)));
typedef unsigned int uint32;

__device__ __forceinline__ ushort rne_bf16(float f) {
  uint32 u = __builtin_bit_cast(uint32, f);
  u += 0x7fffu + ((u >> 16) & 1u);
  return (ushort)(u >> 16);
}

// ---------------- bucketed CSR build ----------------
// unified dst space: disease dsts [0,ND), gene dsts [ND,NTOT). bucket = dst>>8.

__global__ void zero_ints(int* __restrict__ p, int n) {
  int i = blockIdx.x * 256 + threadIdx.x;
  if (i < n) p[i] = 0;
}

// Pass A1: per-bucket edge counts (LDS histogram -> few global atomics)
__global__ void bucket_count(const int* __restrict__ dst_g2d, const int* __restrict__ dst_d2g,
                             int* __restrict__ bcnt) {
  __shared__ int h[NBK];
  for (int j = threadIdx.x; j < NBK; j += 256) h[j] = 0;
  __syncthreads();
  int stride = gridDim.x * 256;
  for (int i = blockIdx.x * 256 + threadIdx.x; i < 2 * NE; i += stride) {
    int d = (i < NE) ? dst_g2d[i] : ND + dst_d2g[i - NE];
    atomicAdd(&h[d >> 8], 1);
  }
  __syncthreads();
  for (int j = threadIdx.x; j < NBK; j += 256)
    if (h[j]) atomicAdd(&bcnt[j], h[j]);
}

// Pass A2: exclusive scan of bucket counts; init cursors
__global__ void bucket_scan(const int* __restrict__ bcnt, int* __restrict__ bbase,
                            int* __restrict__ bcur) {
  __shared__ int s[1024];
  int t = threadIdx.x;
  s[t] = (t < NBK) ? bcnt[t] : 0;
  __syncthreads();
  for (int off = 1; off < 1024; off <<= 1) {
    int v = (t >= off) ? s[t - off] : 0;
    __syncthreads();
    s[t] += v;
    __syncthreads();
  }
  if (t < NBK) {
    int e = (t > 0) ? s[t - 1] : 0;
    bbase[t] = e;
    bcur[t] = e;
  }
  if (t == 0) bbase[NBK] = 2 * NE;
}

// Pass A3: scatter (dst,src) pairs into bucket segments.
__global__ void bucket_scatter(const int* __restrict__ src_g2d, const int* __restrict__ dst_g2d,
                               const int* __restrict__ src_d2g, const int* __restrict__ dst_d2g,
                               int* __restrict__ bcur, int2* __restrict__ pairs) {
  __shared__ int h[NBK];
  __shared__ int base[NBK];
  int e0 = blockIdx.x * EPB;
  int e1 = e0 + EPB;
  if (e1 > 2 * NE) e1 = 2 * NE;
  for (int j = threadIdx.x; j < NBK; j += 256) h[j] = 0;
  __syncthreads();
  for (int i = e0 + threadIdx.x; i < e1; i += 256) {
    int d = (i < NE) ? dst_g2d[i] : ND + dst_d2g[i - NE];
    atomicAdd(&h[d >> 8], 1);
  }
  __syncthreads();
  for (int j = threadIdx.x; j < NBK; j += 256) {
    int c = h[j];
    base[j] = c ? atomicAdd(&bcur[j], c) : 0;
    h[j] = 0;  // reuse as local cursor
  }
  __syncthreads();
  for (int i = e0 + threadIdx.x; i < e1; i += 256) {
    int d, s;
    if (i < NE) {
      d = dst_g2d[i];
      s = src_g2d[i];
    } else {
      d = ND + dst_d2g[i - NE];
      s = src_d2g[i - NE];
    }
    int bkt = d >> 8;
    int p = base[bkt] + atomicAdd(&h[bkt], 1);
    pairs[p] = make_int2(d, s);
  }
}

// Pass B: one block per bucket -> off[] + csr placement
__global__ void bucket_to_csr(const int* __restrict__ bbase, const int2* __restrict__ pairs,
                              int* __restrict__ off, int* __restrict__ csr) {
  __shared__ int cnt[256];
  __shared__ int ss[256];
  int b = blockIdx.x, t = threadIdx.x;
  int n0 = b << 8;
  int s0 = bbase[b], s1 = bbase[b + 1];
  cnt[t] = 0;
  __syncthreads();
  for (int i = s0 + t; i < s1; i += 256) atomicAdd(&cnt[pairs[i].x - n0], 1);
  __syncthreads();
  int x = cnt[t];
  ss[t] = x;
  __syncthreads();
  for (int o = 1; o < 256; o <<= 1) {
    int y = (t >= o) ? ss[t - o] : 0;
    __syncthreads();
    ss[t] += y;
    __syncthreads();
  }
  int abs0 = s0 + ss[t] - x;
  int node = n0 + t;
  if (node < NTOT) off[node] = abs0;
  if (node == NTOT - 1) off[NTOT] = 2 * NE;
  __syncthreads();
  cnt[t] = abs0;  // absolute cursor
  __syncthreads();
  for (int i = s0 + t; i < s1; i += 256) {
    int2 e = pairs[i];
    int p = atomicAdd(&cnt[e.x - n0], 1);
    csr[p] = e.y;
  }
}

// ---------------- fp32 -> bf16 table convert (RNE), both tables in one launch ------------

__global__ void to_bf16_all(const float* __restrict__ xg, const float* __restrict__ xd,
                            ushort* __restrict__ yg, ushort* __restrict__ yd) {
  int i = blockIdx.x * 256 + threadIdx.x;
  if (i >= NTOT * 16) return;
  const float* x;
  ushort* y;
  int j;
  if (i < NG * 16) {
    x = xg; y = yg; j = i;
  } else {
    x = xd; y = yd; j = i - NG * 16;
  }
  const float4* px = (const float4*)x;
  float4 a = px[2 * j], b = px[2 * j + 1];
  float v[8] = {a.x, a.y, a.z, a.w, b.x, b.y, b.z, b.w};
  uint32 u[4];
#pragma unroll
  for (int k = 0; k < 4; k++)
    u[k] = (uint32)rne_bf16(v[2 * k]) | ((uint32)rne_bf16(v[2 * k + 1]) << 16);
  ((int4*)y)[j] = make_int4((int)u[0], (int)u[1], (int)u[2], (int)u[3]);
}

// ---------------- W pre-split: fp32 -> bf16 hi (trunc) + bf16 lo (residual) --------------

__global__ void split_w(const float* __restrict__ Wl, const float* __restrict__ Wr,
                        ushort* __restrict__ WlH, ushort* __restrict__ WlL,
                        ushort* __restrict__ WrH, ushort* __restrict__ WrL) {
  int i = blockIdx.x * 256 + threadIdx.x;
  if (i >= 4 * 128 * 128) return;
  {
    float a = Wl[i];
    uint32 u = __builtin_bit_cast(uint32, a);
    float hf = __builtin_bit_cast(float, u & 0xffff0000u);
    WlH[i] = (ushort)(u >> 16);
    WlL[i] = (ushort)(__builtin_bit_cast(uint32, a - hf) >> 16);
  }
  {
    float a = Wr[i];
    uint32 u = __builtin_bit_cast(uint32, a);
    float hf = __builtin_bit_cast(float, u & 0xffff0000u);
    WrH[i] = (ushort)(u >> 16);
    WrL[i] = (ushort)(__builtin_bit_cast(uint32, a - hf) >> 16);
  }
}

// ---------------- mean aggregation over bf16 rows, unified node space --------------------

__device__ __forceinline__ void acc8(float* a, int4 u) {
  uint32 w;
  w = (uint32)u.x;
  a[0] += __builtin_bit_cast(float, w << 16);
  a[1] += __builtin_bit_cast(float, w & 0xffff0000u);
  w = (uint32)u.y;
  a[2] += __builtin_bit_cast(float, w << 16);
  a[3] += __builtin_bit_cast(float, w & 0xffff0000u);
  w = (uint32)u.z;
  a[4] += __builtin_bit_cast(float, w << 16);
  a[5] += __builtin_bit_cast(float, w & 0xffff0000u);
  w = (uint32)u.w;
  a[6] += __builtin_bit_cast(float, w << 16);
  a[7] += __builtin_bit_cast(float, w & 0xffff0000u);
}

__global__ void agg_comb(const ushort* __restrict__ xg_bf, const ushort* __restrict__ xd_bf,
                         const int* __restrict__ off, const int* __restrict__ csr,
                         ushort* __restrict__ agg_bf) {
  int node = (blockIdx.x * 256 + threadIdx.x) >> 6;
  if (node >= NTOT) return;
  int lane = threadIdx.x & 63;
  const ushort* xsrc = (node < ND) ? xg_bf : xd_bf;
  int e0 = off[node], e1 = off[node + 1];
  int q = lane >> 4, l16 = lane & 15;
  const int4* xs = (const int4*)xsrc;
  float a[8] = {0.f, 0.f, 0.f, 0.f, 0.f, 0.f, 0.f, 0.f};
  int e = e0 + q;
  for (; e + 4 < e1; e += 8) {
    int s0 = csr[e], s1 = csr[e + 4];
    int4 u = xs[(size_t)s0 * 16 + l16];
    int4 v = xs[(size_t)s1 * 16 + l16];
    acc8(a, u);
    acc8(a, v);
  }
  if (e < e1) acc8(a, xs[(size_t)csr[e] * 16 + l16]);
#pragma unroll
  for (int j = 0; j < 8; j++) {
    a[j] += __shfl_xor(a[j], 16);
    a[j] += __shfl_xor(a[j], 32);
  }
  if (q == 0) {
    int deg = e1 - e0;
    float inv = (deg > 0) ? 1.f / (float)deg : 0.f;
    uint32 u[4];
#pragma unroll
    for (int j = 0; j < 4; j++)
      u[j] = (uint32)rne_bf16(a[2 * j] * inv) | ((uint32)rne_bf16(a[2 * j + 1] * inv) << 16);
    *(int4*)&agg_bf[(size_t)node * DIM + l16 * 8] =
        make_int4((int)u[0], (int)u[1], (int)u[2], (int)u[3]);
  }
}

// ---------------- MFMA SAGE update, barrier-free direct-load version ---------------------
// All operands loaded per-lane straight at MFMA-fragment granularity:
//   W fragments (int4) from L1/L2-hot pre-split tables (same addrs in all waves),
//   A fragments (int4) from agg_bf (each row consumed only by its own 4 lanes),
//   X fragments (2x float4) split to bf16 hi/lo in registers.
// No LDS staging in the main loop -> zero __syncthreads -> loads pipeline across
// K-steps with counted vmcnt instead of draining at barriers.
// LDS holds only the wave-private epilogue transpose buffer (no barriers needed).

__device__ __forceinline__ void split8(const float* xp, bf16x8& hi, bf16x8& lo) {
  float4 f0 = *(const float4*)xp;
  float4 f1 = *(const float4*)(xp + 4);
  float v[8] = {f0.x, f0.y, f0.z, f0.w, f1.x, f1.y, f1.z, f1.w};
  uint32 hw[4], lw[4];
#pragma unroll
  for (int j = 0; j < 4; j++) {
    uint32 u0 = __builtin_bit_cast(uint32, v[2 * j]);
    uint32 u1 = __builtin_bit_cast(uint32, v[2 * j + 1]);
    float hf0 = __builtin_bit_cast(float, u0 & 0xffff0000u);
    float hf1 = __builtin_bit_cast(float, u1 & 0xffff0000u);
    uint32 l0 = __builtin_bit_cast(uint32, v[2 * j] - hf0) >> 16;
    uint32 l1 = __builtin_bit_cast(uint32, v[2 * j + 1] - hf1) >> 16;
    hw[j] = (u0 >> 16) | ((u1 >> 16) << 16);
    lw[j] = l0 | (l1 << 16);
  }
  hi = __builtin_bit_cast(bf16x8, make_int4((int)hw[0], (int)hw[1], (int)hw[2], (int)hw[3]));
  lo = __builtin_bit_cast(bf16x8, make_int4((int)lw[0], (int)lw[1], (int)lw[2], (int)lw[3]));
}

__launch_bounds__(256)
__global__ void sage_dual(const ushort* __restrict__ agg_bf, const float* __restrict__ xd,
                          const float* __restrict__ xg, const ushort* __restrict__ WlH,
                          const ushort* __restrict__ WlL, const ushort* __restrict__ WrH,
                          const ushort* __restrict__ WrL, const float* __restrict__ bias_all,
                          float* __restrict__ outd, float* __restrict__ outg,
                          ushort* __restrict__ xbf_d, ushort* __restrict__ xbf_g, int layer,
                          int relu, int write_bf) {
  __shared__ __align__(16) float smem[4 * 16 * 132];  // per-wave transpose buffers only

  int b = blockIdx.x;
  const float* X;
  float* O;
  ushort* OBF;
  int n, set, r0g, cbase;
  if (b < NBT_D) {
    X = xd; O = outd; OBF = xbf_d; n = ND; set = layer * 2; r0g = b * 128; cbase = 0;
  } else {
    X = xg; O = outg; OBF = xbf_g; n = NG; set = layer * 2 + 1;
    r0g = (b - NBT_D) * 128; cbase = ND;
  }
  const ushort* WH[2] = {WlH + set * 16384, WrH + set * 16384};
  const ushort* WL[2] = {WlL + set * 16384, WrL + set * 16384};
  const float* bias = bias_all + set * 128;

  int tid = threadIdx.x;
  int wave = tid >> 6, lane = tid & 63;
  int m = lane & 15, q = lane >> 4;

  int arow0 = wave * 32 + m;
  int arow1 = arow0 + 16;
  int r0 = r0g + arow0;
  if (r0 >= n) r0 = n - 1;
  int r1 = r0g + arow1;
  if (r1 >= n) r1 = n - 1;

  f32x4 acc[2][8];
#pragma unroll
  for (int mt = 0; mt < 2; mt++)
#pragma unroll
    for (int nt = 0; nt < 8; nt++) acc[mt][nt] = (f32x4)0.f;

  // ---- ph0: neighbors (bf16 agg rows x (Wl hi + lo)) ----
  {
    const ushort* Wh = WH[0];
    const ushort* Wl = WL[0];
#pragma unroll
    for (int ks = 0; ks < 4; ks++) {
      int kc = ks * 32 + q * 8;
      bf16x8 a0 =
          __builtin_bit_cast(bf16x8, *(const int4*)&agg_bf[(size_t)(cbase + r0) * DIM + kc]);
      bf16x8 a1 =
          __builtin_bit_cast(bf16x8, *(const int4*)&agg_bf[(size_t)(cbase + r1) * DIM + kc]);
#pragma unroll
      for (int nt = 0; nt < 8; nt++) {
        int nn = nt * 16 + m;
        bf16x8 bh = __builtin_bit_cast(bf16x8, *(const int4*)&Wh[nn * 128 + kc]);
        bf16x8 bl = __builtin_bit_cast(bf16x8, *(const int4*)&Wl[nn * 128 + kc]);
        acc[0][nt] = __builtin_amdgcn_mfma_f32_16x16x32_bf16(a0, bh, acc[0][nt], 0, 0, 0);
        acc[1][nt] = __builtin_amdgcn_mfma_f32_16x16x32_bf16(a1, bh, acc[1][nt], 0, 0, 0);
        acc[0][nt] = __builtin_amdgcn_mfma_f32_16x16x32_bf16(a0, bl, acc[0][nt], 0, 0, 0);
        acc[1][nt] = __builtin_amdgcn_mfma_f32_16x16x32_bf16(a1, bl, acc[1][nt], 0, 0, 0);
      }
    }
  }

  // ---- ph1: root X (fp32 rows split hi/lo in-register x (Wr hi + lo)) ----
  {
    const ushort* Wh = WH[1];
    const ushort* Wl = WL[1];
#pragma unroll
    for (int ks = 0; ks < 4; ks++) {
      int kc = ks * 32 + q * 8;
      bf16x8 ah0, al0, ah1, al1;
      split8(&X[(size_t)r0 * DIM + kc], ah0, al0);
      split8(&X[(size_t)r1 * DIM + kc], ah1, al1);
#pragma unroll
      for (int nt = 0; nt < 8; nt++) {
        int nn = nt * 16 + m;
        bf16x8 bh = __builtin_bit_cast(bf16x8, *(const int4*)&Wh[nn * 128 + kc]);
        bf16x8 bl = __builtin_bit_cast(bf16x8, *(const int4*)&Wl[nn * 128 + kc]);
        acc[0][nt] = __builtin_amdgcn_mfma_f32_16x16x32_bf16(ah0, bh, acc[0][nt], 0, 0, 0);
        acc[1][nt] = __builtin_amdgcn_mfma_f32_16x16x32_bf16(ah1, bh, acc[1][nt], 0, 0, 0);
        acc[0][nt] = __builtin_amdgcn_mfma_f32_16x16x32_bf16(ah0, bl, acc[0][nt], 0, 0, 0);
        acc[1][nt] = __builtin_amdgcn_mfma_f32_16x16x32_bf16(ah1, bl, acc[1][nt], 0, 0, 0);
        acc[0][nt] = __builtin_amdgcn_mfma_f32_16x16x32_bf16(al0, bh, acc[0][nt], 0, 0, 0);
        acc[1][nt] = __builtin_amdgcn_mfma_f32_16x16x32_bf16(al1, bh, acc[1][nt], 0, 0, 0);
      }
    }
  }

  // ---- epilogue: bias, relu, L2-normalize, skipsum, store (+ optional bf16 copy) ----
  float bb[8];
#pragma unroll
  for (int nt = 0; nt < 8; nt++) bb[nt] = bias[nt * 16 + m];

  const int S = 132;
  float* wbuf = smem + wave * (16 * S);  // wave-private: no barriers needed

  int half = lane >> 5;
  int c4 = (lane & 31) * 4;

#pragma unroll
  for (int mt = 0; mt < 2; mt++) {
#pragma unroll
    for (int reg = 0; reg < 4; reg++) {
      float h[8];
      float ss = 0.f;
#pragma unroll
      for (int nt = 0; nt < 8; nt++) {
        float v = acc[mt][nt][reg] + bb[nt];
        if (relu) v = fmaxf(v, 0.f);
        h[nt] = v;
        ss += v * v;
      }
      ss += __shfl_xor(ss, 1);
      ss += __shfl_xor(ss, 2);
      ss += __shfl_xor(ss, 4);
      ss += __shfl_xor(ss, 8);
      float inv = 1.f / fmaxf(sqrtf(ss), EPSN);
      int rrel = q * 4 + reg;
#pragma unroll
      for (int nt = 0; nt < 8; nt++) wbuf[rrel * S + nt * 16 + m] = h[nt] * inv;
    }
#pragma unroll
    for (int i = 0; i < 8; i++) {
      int rrel = i * 2 + half;
      int R = r0g + wave * 32 + mt * 16 + rrel;
      if (R < n) {
        f32x4 hv = *(const f32x4*)&wbuf[rrel * S + c4];
        float4 xr = *(const float4*)&X[(size_t)R * DIM + c4];
        float4 o;
        o.x = hv[0] + xr.x;
        o.y = hv[1] + xr.y;
        o.z = hv[2] + xr.z;
        o.w = hv[3] + xr.w;
        *(float4*)&O[(size_t)R * DIM + c4] = o;
        if (write_bf) {
          int2 pk = make_int2((int)((uint32)rne_bf16(o.x) | ((uint32)rne_bf16(o.y) << 16)),
                              (int)((uint32)rne_bf16(o.z) | ((uint32)rne_bf16(o.w) << 16)));
          *(int2*)&OBF[(size_t)R * DIM + c4] = pk;
        }
      }
    }
  }
}

// ---------------- launch ----------------

extern "C" void kernel_launch(void* const* d_in, const int* in_sizes, int n_in,
                              void* d_out, int out_size, void* d_ws, size_t ws_size,
                              hipStream_t stream) {
  const float* xg0 = (const float*)d_in[0];
  const float* xd0 = (const float*)d_in[1];
  const float* Wl = (const float*)d_in[2];
  const float* Wr = (const float*)d_in[3];
  const float* bs = (const float*)d_in[4];
  const int* src_g2d = (const int*)d_in[5];
  const int* dst_g2d = (const int*)d_in[6];
  const int* src_d2g = (const int*)d_in[7];
  const int* dst_d2g = (const int*)d_in[8];

  float* out_xg = (float*)d_out;
  float* out_xd = (float*)d_out + (size_t)NG * DIM;

  char* p = (char*)d_ws;
  auto alloc = [&](size_t bytes) -> char* {
    char* q = p;
    p += (bytes + 255) & ~(size_t)255;
    return q;
  };
  int* off = (int*)alloc((NTOT + 1) * 4);
  int* csr = (int*)alloc((size_t)2 * NE * 4);
  int* bcnt = (int*)alloc(NBK * 4);
  int* bbase = (int*)alloc((NBK + 1) * 4);
  int* bcur = (int*)alloc(NBK * 4);
  // pairs (12.8 MB, used only during CSR build) aliases agg_bf (38.4 MB, used after)
  char* big = alloc((size_t)NTOT * DIM * 2);
  int2* pairs = (int2*)big;
  ushort* agg_bf = (ushort*)big;
  ushort* xg_bf = (ushort*)alloc((size_t)NG * DIM * 2);
  ushort* xd_bf = (ushort*)alloc((size_t)ND * DIM * 2);
  ushort* WlH = (ushort*)alloc((size_t)4 * 128 * 128 * 2);
  ushort* WlL = (ushort*)alloc((size_t)4 * 128 * 128 * 2);
  ushort* WrH = (ushort*)alloc((size_t)4 * 128 * 128 * 2);
  ushort* WrL = (ushort*)alloc((size_t)4 * 128 * 128 * 2);

  const int TB = 256;

  split_w<<<256, TB, 0, stream>>>(Wl, Wr, WlH, WlL, WrH, WrL);
  to_bf16_all<<<(NTOT * 16 + TB - 1) / TB, TB, 0, stream>>>(xg0, xd0, xg_bf, xd_bf);

  // bucketed CSR build
  zero_ints<<<(NBK + TB - 1) / TB, TB, 0, stream>>>(bcnt, NBK);
  bucket_count<<<256, TB, 0, stream>>>(dst_g2d, dst_d2g, bcnt);
  bucket_scan<<<1, 1024, 0, stream>>>(bcnt, bbase, bcur);
  bucket_scatter<<<SCB, TB, 0, stream>>>(src_g2d, dst_g2d, src_d2g, dst_d2g, bcur, pairs);
  bucket_to_csr<<<NBK, TB, 0, stream>>>(bbase, pairs, off, csr);

  int aggBlocks = NTOT / 4;        // 37500
  int sageBlocks = NBT_D + NBT_G;  // 1173

  // layer 0 (relu); sage also emits bf16 copy of out for layer-1 gather
  agg_comb<<<aggBlocks, TB, 0, stream>>>(xg_bf, xd_bf, off, csr, agg_bf);
  sage_dual<<<sageBlocks, TB, 0, stream>>>(agg_bf, xd0, xg0, WlH, WlL, WrH, WrL, bs, out_xd,
                                           out_xg, xd_bf, xg_bf, 0, 1, 1);

  // layer 1 (no relu), in-place on d_out
  agg_comb<<<aggBlocks, TB, 0, stream>>>(xg_bf, xd_bf, off, csr, agg_bf);
  sage_dual<<<sageBlocks, TB, 0, stream>>>(agg_bf, out_xd, out_xg, WlH, WlL, WrH, WrL, bs,
                                           out_xd, out_xg, xd_bf, xg_bf, 1, 0, 0);
}

// Round 3
// 539.305 us; speedup vs baseline: 1.2766x; 1.1501x over previous
//
#include <hip/hip_runtime.h>
#include <math.h>

#define NG 100000
#define ND 50000
#define NTOT 150000
#define DIM 128
#define NE 800000
#define EPSN 1e-12f

#define RPB 256     // rows per sage block
#define NBT_D2 196  // ceil(ND/256)
#define NBT_G2 391  // ceil(NG/256)

#define NBK 586    // ceil(NTOT/256) buckets of 256 dst nodes
#define SCB 128    // scatter blocks
#define EPB 12500  // edges per scatter block = ceil(2*NE/SCB)

typedef __bf16 bf16x8 __attribute__((ext_vector_type(8)));
typedef float f32x4 __attribute__((ext_vector_type(4)));
typedef unsigned int uint32;

__device__ __forceinline__ ushort rne_bf16(float f) {
  uint32 u = __builtin_bit_cast(uint32, f);
  u += 0x7fffu + ((u >> 16) & 1u);
  return (ushort)(u >> 16);
}

// ---------------- bucketed CSR build ----------------
// unified dst space: disease dsts [0,ND), gene dsts [ND,NTOT). bucket = dst>>8.

__global__ void zero_ints(int* __restrict__ p, int n) {
  int i = blockIdx.x * 256 + threadIdx.x;
  if (i < n) p[i] = 0;
}

__global__ void bucket_count(const int* __restrict__ dst_g2d, const int* __restrict__ dst_d2g,
                             int* __restrict__ bcnt) {
  __shared__ int h[NBK];
  for (int j = threadIdx.x; j < NBK; j += 256) h[j] = 0;
  __syncthreads();
  int stride = gridDim.x * 256;
  for (int i = blockIdx.x * 256 + threadIdx.x; i < 2 * NE; i += stride) {
    int d = (i < NE) ? dst_g2d[i] : ND + dst_d2g[i - NE];
    atomicAdd(&h[d >> 8], 1);
  }
  __syncthreads();
  for (int j = threadIdx.x; j < NBK; j += 256)
    if (h[j]) atomicAdd(&bcnt[j], h[j]);
}

__global__ void bucket_scan(const int* __restrict__ bcnt, int* __restrict__ bbase,
                            int* __restrict__ bcur) {
  __shared__ int s[1024];
  int t = threadIdx.x;
  s[t] = (t < NBK) ? bcnt[t] : 0;
  __syncthreads();
  for (int off = 1; off < 1024; off <<= 1) {
    int v = (t >= off) ? s[t - off] : 0;
    __syncthreads();
    s[t] += v;
    __syncthreads();
  }
  if (t < NBK) {
    int e = (t > 0) ? s[t - 1] : 0;
    bbase[t] = e;
    bcur[t] = e;
  }
  if (t == 0) bbase[NBK] = 2 * NE;
}

__global__ void bucket_scatter(const int* __restrict__ src_g2d, const int* __restrict__ dst_g2d,
                               const int* __restrict__ src_d2g, const int* __restrict__ dst_d2g,
                               int* __restrict__ bcur, int2* __restrict__ pairs) {
  __shared__ int h[NBK];
  __shared__ int base[NBK];
  int e0 = blockIdx.x * EPB;
  int e1 = e0 + EPB;
  if (e1 > 2 * NE) e1 = 2 * NE;
  for (int j = threadIdx.x; j < NBK; j += 256) h[j] = 0;
  __syncthreads();
  for (int i = e0 + threadIdx.x; i < e1; i += 256) {
    int d = (i < NE) ? dst_g2d[i] : ND + dst_d2g[i - NE];
    atomicAdd(&h[d >> 8], 1);
  }
  __syncthreads();
  for (int j = threadIdx.x; j < NBK; j += 256) {
    int c = h[j];
    base[j] = c ? atomicAdd(&bcur[j], c) : 0;
    h[j] = 0;  // reuse as local cursor
  }
  __syncthreads();
  for (int i = e0 + threadIdx.x; i < e1; i += 256) {
    int d, s;
    if (i < NE) {
      d = dst_g2d[i];
      s = src_g2d[i];
    } else {
      d = ND + dst_d2g[i - NE];
      s = src_d2g[i - NE];
    }
    int bkt = d >> 8;
    int p = base[bkt] + atomicAdd(&h[bkt], 1);
    pairs[p] = make_int2(d, s);
  }
}

__global__ void bucket_to_csr(const int* __restrict__ bbase, const int2* __restrict__ pairs,
                              int* __restrict__ off, int* __restrict__ csr) {
  __shared__ int cnt[256];
  __shared__ int ss[256];
  int b = blockIdx.x, t = threadIdx.x;
  int n0 = b << 8;
  int s0 = bbase[b], s1 = bbase[b + 1];
  cnt[t] = 0;
  __syncthreads();
  for (int i = s0 + t; i < s1; i += 256) atomicAdd(&cnt[pairs[i].x - n0], 1);
  __syncthreads();
  int x = cnt[t];
  ss[t] = x;
  __syncthreads();
  for (int o = 1; o < 256; o <<= 1) {
    int y = (t >= o) ? ss[t - o] : 0;
    __syncthreads();
    ss[t] += y;
    __syncthreads();
  }
  int abs0 = s0 + ss[t] - x;
  int node = n0 + t;
  if (node < NTOT) off[node] = abs0;
  if (node == NTOT - 1) off[NTOT] = 2 * NE;
  __syncthreads();
  cnt[t] = abs0;  // absolute cursor
  __syncthreads();
  for (int i = s0 + t; i < s1; i += 256) {
    int2 e = pairs[i];
    int p = atomicAdd(&cnt[e.x - n0], 1);
    csr[p] = e.y;
  }
}

// ---------------- fp32 -> bf16 table convert (RNE), both tables in one launch ------------

__global__ void to_bf16_all(const float* __restrict__ xg, const float* __restrict__ xd,
                            ushort* __restrict__ yg, ushort* __restrict__ yd) {
  int i = blockIdx.x * 256 + threadIdx.x;
  if (i >= NTOT * 16) return;
  const float* x;
  ushort* y;
  int j;
  if (i < NG * 16) {
    x = xg; y = yg; j = i;
  } else {
    x = xd; y = yd; j = i - NG * 16;
  }
  const float4* px = (const float4*)x;
  float4 a = px[2 * j], b = px[2 * j + 1];
  float v[8] = {a.x, a.y, a.z, a.w, b.x, b.y, b.z, b.w};
  uint32 u[4];
#pragma unroll
  for (int k = 0; k < 4; k++)
    u[k] = (uint32)rne_bf16(v[2 * k]) | ((uint32)rne_bf16(v[2 * k + 1]) << 16);
  ((int4*)y)[j] = make_int4((int)u[0], (int)u[1], (int)u[2], (int)u[3]);
}

// ---------------- W pre-split: fp32 -> bf16 hi (trunc) + bf16 lo (residual) --------------

__global__ void split_w(const float* __restrict__ Wl, const float* __restrict__ Wr,
                        ushort* __restrict__ WlH, ushort* __restrict__ WlL,
                        ushort* __restrict__ WrH, ushort* __restrict__ WrL) {
  int i = blockIdx.x * 256 + threadIdx.x;
  if (i >= 4 * 128 * 128) return;
  {
    float a = Wl[i];
    uint32 u = __builtin_bit_cast(uint32, a);
    float hf = __builtin_bit_cast(float, u & 0xffff0000u);
    WlH[i] = (ushort)(u >> 16);
    WlL[i] = (ushort)(__builtin_bit_cast(uint32, a - hf) >> 16);
  }
  {
    float a = Wr[i];
    uint32 u = __builtin_bit_cast(uint32, a);
    float hf = __builtin_bit_cast(float, u & 0xffff0000u);
    WrH[i] = (ushort)(u >> 16);
    WrL[i] = (ushort)(__builtin_bit_cast(uint32, a - hf) >> 16);
  }
}

// ---------------- mean aggregation over bf16 rows, unified node space --------------------

__device__ __forceinline__ void acc8(float* a, int4 u) {
  uint32 w;
  w = (uint32)u.x;
  a[0] += __builtin_bit_cast(float, w << 16);
  a[1] += __builtin_bit_cast(float, w & 0xffff0000u);
  w = (uint32)u.y;
  a[2] += __builtin_bit_cast(float, w << 16);
  a[3] += __builtin_bit_cast(float, w & 0xffff0000u);
  w = (uint32)u.z;
  a[4] += __builtin_bit_cast(float, w << 16);
  a[5] += __builtin_bit_cast(float, w & 0xffff0000u);
  w = (uint32)u.w;
  a[6] += __builtin_bit_cast(float, w << 16);
  a[7] += __builtin_bit_cast(float, w & 0xffff0000u);
}

__global__ void agg_comb(const ushort* __restrict__ xg_bf, const ushort* __restrict__ xd_bf,
                         const int* __restrict__ off, const int* __restrict__ csr,
                         ushort* __restrict__ agg_bf) {
  int node = (blockIdx.x * 256 + threadIdx.x) >> 6;
  if (node >= NTOT) return;
  int lane = threadIdx.x & 63;
  const ushort* xsrc = (node < ND) ? xg_bf : xd_bf;
  int e0 = off[node], e1 = off[node + 1];
  int q = lane >> 4, l16 = lane & 15;
  const int4* xs = (const int4*)xsrc;
  float a[8] = {0.f, 0.f, 0.f, 0.f, 0.f, 0.f, 0.f, 0.f};
  int e = e0 + q;
  for (; e + 4 < e1; e += 8) {
    int s0 = csr[e], s1 = csr[e + 4];
    int4 u = xs[(size_t)s0 * 16 + l16];
    int4 v = xs[(size_t)s1 * 16 + l16];
    acc8(a, u);
    acc8(a, v);
  }
  if (e < e1) acc8(a, xs[(size_t)csr[e] * 16 + l16]);
#pragma unroll
  for (int j = 0; j < 8; j++) {
    a[j] += __shfl_xor(a[j], 16);
    a[j] += __shfl_xor(a[j], 32);
  }
  if (q == 0) {
    int deg = e1 - e0;
    float inv = (deg > 0) ? 1.f / (float)deg : 0.f;
    uint32 u[4];
#pragma unroll
    for (int j = 0; j < 4; j++)
      u[j] = (uint32)rne_bf16(a[2 * j] * inv) | ((uint32)rne_bf16(a[2 * j + 1] * inv) << 16);
    *(int4*)&agg_bf[(size_t)node * DIM + l16 * 8] =
        make_int4((int)u[0], (int)u[1], (int)u[2], (int)u[3]);
  }
}

// ---------------- MFMA SAGE update: W fully LDS-resident, 256 rows/block ------------------
// All four W planes (Wl hi/lo, Wr hi/lo; 32 KB each = 128 KB) are staged into LDS ONCE per
// block (reg-staged, XOR-swizzled ds_write), then the MFMA main loop is barrier-free:
//   B fragments from LDS (swizzled ds_read_b128, conflict-free),
//   A fragments (int4 from agg_bf) and X rows (fp32, split hi/lo in-register) direct.
// 256 rows/block, 64 rows/wave (acc[4][8]) -> each B fragment feeds 8-12 MFMAs.
// 1 block/CU (LDS-limited); __launch_bounds__(256,1) frees VGPR budget for deep MLP.

__device__ __forceinline__ void split8(const float* xp, bf16x8& hi, bf16x8& lo) {
  float4 f0 = *(const float4*)xp;
  float4 f1 = *(const float4*)(xp + 4);
  float v[8] = {f0.x, f0.y, f0.z, f0.w, f1.x, f1.y, f1.z, f1.w};
  uint32 hw[4], lw[4];
#pragma unroll
  for (int j = 0; j < 4; j++) {
    uint32 u0 = __builtin_bit_cast(uint32, v[2 * j]);
    uint32 u1 = __builtin_bit_cast(uint32, v[2 * j + 1]);
    float hf0 = __builtin_bit_cast(float, u0 & 0xffff0000u);
    float hf1 = __builtin_bit_cast(float, u1 & 0xffff0000u);
    uint32 l0 = __builtin_bit_cast(uint32, v[2 * j] - hf0) >> 16;
    uint32 l1 = __builtin_bit_cast(uint32, v[2 * j + 1] - hf1) >> 16;
    hw[j] = (u0 >> 16) | ((u1 >> 16) << 16);
    lw[j] = l0 | (l1 << 16);
  }
  hi = __builtin_bit_cast(bf16x8, make_int4((int)hw[0], (int)hw[1], (int)hw[2], (int)hw[3]));
  lo = __builtin_bit_cast(bf16x8, make_int4((int)lw[0], (int)lw[1], (int)lw[2], (int)lw[3]));
}

__launch_bounds__(256, 1)
__global__ void sage_dual(const ushort* __restrict__ agg_bf, const float* __restrict__ xd,
                          const float* __restrict__ xg, const ushort* __restrict__ WlH,
                          const ushort* __restrict__ WlL, const ushort* __restrict__ WrH,
                          const ushort* __restrict__ WrL, const float* __restrict__ bias_all,
                          float* __restrict__ outd, float* __restrict__ outg,
                          ushort* __restrict__ xbf_d, ushort* __restrict__ xbf_g, int layer,
                          int relu, int write_bf) {
  __shared__ __align__(16) char smem[131072];  // 4 W planes of 32 KB; epilogue aliases

  int b = blockIdx.x;
  const float* X;
  float* O;
  ushort* OBF;
  int n, set, r0g, cbase;
  if (b < NBT_D2) {
    X = xd; O = outd; OBF = xbf_d; n = ND; set = layer * 2; r0g = b * RPB; cbase = 0;
  } else {
    X = xg; O = outg; OBF = xbf_g; n = NG; set = layer * 2 + 1;
    r0g = (b - NBT_D2) * RPB; cbase = ND;
  }
  const ushort* Wplanes[4] = {WlH + set * 16384, WlL + set * 16384, WrH + set * 16384,
                              WrL + set * 16384};
  const float* bias = bias_all + set * 128;

  int tid = threadIdx.x;
  int wave = tid >> 6, lane = tid & 63;
  int m = lane & 15, q = lane >> 4;

  // ---- stage all 4 W planes into LDS (swizzled writes) ----
#pragma unroll
  for (int i = 0; i < 32; i++) {
    int c = tid + i * 256;          // chunk of 16B; 8192 chunks total
    int p = c >> 11;                // plane 0..3
    int Bl = (c & 2047) * 16;       // plane-local byte offset (row = Bl>>8)
    int4 v = *(const int4*)((const char*)Wplanes[p] + Bl);
    int dst = p * 32768 + (Bl ^ (((Bl >> 8) & 7) << 4));
    *(int4*)(smem + dst) = v;
  }
  __syncthreads();

  f32x4 acc[4][8];
#pragma unroll
  for (int mt = 0; mt < 4; mt++)
#pragma unroll
    for (int nt = 0; nt < 8; nt++) acc[mt][nt] = (f32x4)0.f;

  int rb = r0g + wave * 64;

  // ---- ph0: neighbors (bf16 agg rows x (Wl hi + lo) from LDS) ----
#pragma unroll
  for (int ks = 0; ks < 4; ks++) {
    int kc = ks * 32 + q * 8;   // ushort col for A
    int kb = ks * 64 + q * 16;  // byte col for W LDS
    bf16x8 a[4];
#pragma unroll
    for (int mt = 0; mt < 4; mt++) {
      int r = rb + mt * 16 + m;
      if (r >= n) r = n - 1;
      a[mt] = __builtin_bit_cast(bf16x8, *(const int4*)&agg_bf[(size_t)(cbase + r) * DIM + kc]);
    }
#pragma unroll
    for (int nt = 0; nt < 8; nt++) {
      int nn = nt * 16 + m;
      int wb = (nn * 256 + kb) ^ ((nn & 7) << 4);
      bf16x8 bh = *(const bf16x8*)(smem + wb);
      bf16x8 bl = *(const bf16x8*)(smem + 32768 + wb);
#pragma unroll
      for (int mt = 0; mt < 4; mt++) {
        acc[mt][nt] = __builtin_amdgcn_mfma_f32_16x16x32_bf16(a[mt], bh, acc[mt][nt], 0, 0, 0);
        acc[mt][nt] = __builtin_amdgcn_mfma_f32_16x16x32_bf16(a[mt], bl, acc[mt][nt], 0, 0, 0);
      }
    }
  }

  // ---- ph1: root X (fp32 rows split hi/lo in-register x (Wr hi + lo) from LDS) ----
#pragma unroll
  for (int ks = 0; ks < 4; ks++) {
    int kc = ks * 32 + q * 8;
    int kb = ks * 64 + q * 16;
    bf16x8 ah[4], al[4];
#pragma unroll
    for (int mt = 0; mt < 4; mt++) {
      int r = rb + mt * 16 + m;
      if (r >= n) r = n - 1;
      split8(&X[(size_t)r * DIM + kc], ah[mt], al[mt]);
    }
#pragma unroll
    for (int nt = 0; nt < 8; nt++) {
      int nn = nt * 16 + m;
      int wb = (nn * 256 + kb) ^ ((nn & 7) << 4);
      bf16x8 bh = *(const bf16x8*)(smem + 65536 + wb);
      bf16x8 bl = *(const bf16x8*)(smem + 98304 + wb);
#pragma unroll
      for (int mt = 0; mt < 4; mt++) {
        acc[mt][nt] = __builtin_amdgcn_mfma_f32_16x16x32_bf16(ah[mt], bh, acc[mt][nt], 0, 0, 0);
        acc[mt][nt] = __builtin_amdgcn_mfma_f32_16x16x32_bf16(ah[mt], bl, acc[mt][nt], 0, 0, 0);
        acc[mt][nt] = __builtin_amdgcn_mfma_f32_16x16x32_bf16(al[mt], bh, acc[mt][nt], 0, 0, 0);
      }
    }
  }

  __syncthreads();  // all waves done reading W LDS; epilogue aliases it

  // ---- epilogue: bias, relu, L2-normalize, skipsum, store (+ optional bf16 copy) ----
  float bb[8];
#pragma unroll
  for (int nt = 0; nt < 8; nt++) bb[nt] = bias[nt * 16 + m];

  const int S = 132;
  float* wbuf = (float*)smem + wave * (16 * S);  // wave-private: no barriers needed

  int half = lane >> 5;
  int c4 = (lane & 31) * 4;

#pragma unroll
  for (int mt = 0; mt < 4; mt++) {
#pragma unroll
    for (int reg = 0; reg < 4; reg++) {
      float h[8];
      float ss = 0.f;
#pragma unroll
      for (int nt = 0; nt < 8; nt++) {
        float v = acc[mt][nt][reg] + bb[nt];
        if (relu) v = fmaxf(v, 0.f);
        h[nt] = v;
        ss += v * v;
      }
      ss += __shfl_xor(ss, 1);
      ss += __shfl_xor(ss, 2);
      ss += __shfl_xor(ss, 4);
      ss += __shfl_xor(ss, 8);
      float inv = 1.f / fmaxf(sqrtf(ss), EPSN);
      int rrel = q * 4 + reg;
#pragma unroll
      for (int nt = 0; nt < 8; nt++) wbuf[rrel * S + nt * 16 + m] = h[nt] * inv;
    }
#pragma unroll
    for (int i = 0; i < 8; i++) {
      int rrel = i * 2 + half;
      int R = rb + mt * 16 + rrel;
      if (R < n) {
        f32x4 hv = *(const f32x4*)&wbuf[rrel * S + c4];
        float4 xr = *(const float4*)&X[(size_t)R * DIM + c4];
        float4 o;
        o.x = hv[0] + xr.x;
        o.y = hv[1] + xr.y;
        o.z = hv[2] + xr.z;
        o.w = hv[3] + xr.w;
        *(float4*)&O[(size_t)R * DIM + c4] = o;
        if (write_bf) {
          int2 pk = make_int2((int)((uint32)rne_bf16(o.x) | ((uint32)rne_bf16(o.y) << 16)),
                              (int)((uint32)rne_bf16(o.z) | ((uint32)rne_bf16(o.w) << 16)));
          *(int2*)&OBF[(size_t)R * DIM + c4] = pk;
        }
      }
    }
  }
}

// ---------------- launch ----------------

extern "C" void kernel_launch(void* const* d_in, const int* in_sizes, int n_in,
                              void* d_out, int out_size, void* d_ws, size_t ws_size,
                              hipStream_t stream) {
  const float* xg0 = (const float*)d_in[0];
  const float* xd0 = (const float*)d_in[1];
  const float* Wl = (const float*)d_in[2];
  const float* Wr = (const float*)d_in[3];
  const float* bs = (const float*)d_in[4];
  const int* src_g2d = (const int*)d_in[5];
  const int* dst_g2d = (const int*)d_in[6];
  const int* src_d2g = (const int*)d_in[7];
  const int* dst_d2g = (const int*)d_in[8];

  float* out_xg = (float*)d_out;
  float* out_xd = (float*)d_out + (size_t)NG * DIM;

  char* p = (char*)d_ws;
  auto alloc = [&](size_t bytes) -> char* {
    char* q = p;
    p += (bytes + 255) & ~(size_t)255;
    return q;
  };
  int* off = (int*)alloc((NTOT + 1) * 4);
  int* csr = (int*)alloc((size_t)2 * NE * 4);
  int* bcnt = (int*)alloc(NBK * 4);
  int* bbase = (int*)alloc((NBK + 1) * 4);
  int* bcur = (int*)alloc(NBK * 4);
  // pairs (12.8 MB, used only during CSR build) aliases agg_bf (38.4 MB, used after)
  char* big = alloc((size_t)NTOT * DIM * 2);
  int2* pairs = (int2*)big;
  ushort* agg_bf = (ushort*)big;
  ushort* xg_bf = (ushort*)alloc((size_t)NG * DIM * 2);
  ushort* xd_bf = (ushort*)alloc((size_t)ND * DIM * 2);
  ushort* WlH = (ushort*)alloc((size_t)4 * 128 * 128 * 2);
  ushort* WlL = (ushort*)alloc((size_t)4 * 128 * 128 * 2);
  ushort* WrH = (ushort*)alloc((size_t)4 * 128 * 128 * 2);
  ushort* WrL = (ushort*)alloc((size_t)4 * 128 * 128 * 2);

  const int TB = 256;

  split_w<<<256, TB, 0, stream>>>(Wl, Wr, WlH, WlL, WrH, WrL);
  to_bf16_all<<<(NTOT * 16 + TB - 1) / TB, TB, 0, stream>>>(xg0, xd0, xg_bf, xd_bf);

  // bucketed CSR build
  zero_ints<<<(NBK + TB - 1) / TB, TB, 0, stream>>>(bcnt, NBK);
  bucket_count<<<256, TB, 0, stream>>>(dst_g2d, dst_d2g, bcnt);
  bucket_scan<<<1, 1024, 0, stream>>>(bcnt, bbase, bcur);
  bucket_scatter<<<SCB, TB, 0, stream>>>(src_g2d, dst_g2d, src_d2g, dst_d2g, bcur, pairs);
  bucket_to_csr<<<NBK, TB, 0, stream>>>(bbase, pairs, off, csr);

  int aggBlocks = NTOT / 4;          // 37500
  int sageBlocks = NBT_D2 + NBT_G2;  // 587

  // layer 0 (relu); sage also emits bf16 copy of out for layer-1 gather
  agg_comb<<<aggBlocks, TB, 0, stream>>>(xg_bf, xd_bf, off, csr, agg_bf);
  sage_dual<<<sageBlocks, TB, 0, stream>>>(agg_bf, xd0, xg0, WlH, WlL, WrH, WrL, bs, out_xd,
                                           out_xg, xd_bf, xg_bf, 0, 1, 1);

  // layer 1 (no relu), in-place on d_out
  agg_comb<<<aggBlocks, TB, 0, stream>>>(xg_bf, xd_bf, off, csr, agg_bf);
  sage_dual<<<sageBlocks, TB, 0, stream>>>(agg_bf, out_xd, out_xg, WlH, WlL, WrH, WrL, bs,
                                           out_xd, out_xg, xd_bf, xg_bf, 1, 0, 0);
}

// Round 4
// 483.631 us; speedup vs baseline: 1.4235x; 1.1151x over previous
//
#include <hip/hip_runtime.h>
#include <math.h>

#define NG 100000
#define ND 50000
#define NTOT 150000
#define DIM 128
#define NE 800000
#define EPSN 1e-12f

#define RPB 256     // rows per sage block
#define NBT_D2 196  // ceil(ND/256)
#define NBT_G2 391  // ceil(NG/256)

#define NBK 586    // ceil(NTOT/256) buckets of 256 dst nodes
#define SCB 128    // scatter blocks
#define EPB 12500  // edges per scatter block = ceil(2*NE/SCB)

typedef __bf16 bf16x8 __attribute__((ext_vector_type(8)));
typedef float f32x4 __attribute__((ext_vector_type(4)));
typedef unsigned int uint32;

__device__ __forceinline__ ushort rne_bf16(float f) {
  uint32 u = __builtin_bit_cast(uint32, f);
  u += 0x7fffu + ((u >> 16) & 1u);
  return (ushort)(u >> 16);
}

// ---------------- bucketed CSR build ----------------
// unified dst space: disease dsts [0,ND), gene dsts [ND,NTOT). bucket = dst>>8.

__global__ void zero_ints(int* __restrict__ p, int n) {
  int i = blockIdx.x * 256 + threadIdx.x;
  if (i < n) p[i] = 0;
}

__global__ void bucket_count(const int* __restrict__ dst_g2d, const int* __restrict__ dst_d2g,
                             int* __restrict__ bcnt) {
  __shared__ int h[NBK];
  for (int j = threadIdx.x; j < NBK; j += 256) h[j] = 0;
  __syncthreads();
  int stride = gridDim.x * 256;
  for (int i = blockIdx.x * 256 + threadIdx.x; i < 2 * NE; i += stride) {
    int d = (i < NE) ? dst_g2d[i] : ND + dst_d2g[i - NE];
    atomicAdd(&h[d >> 8], 1);
  }
  __syncthreads();
  for (int j = threadIdx.x; j < NBK; j += 256)
    if (h[j]) atomicAdd(&bcnt[j], h[j]);
}

__global__ void bucket_scan(const int* __restrict__ bcnt, int* __restrict__ bbase,
                            int* __restrict__ bcur) {
  __shared__ int s[1024];
  int t = threadIdx.x;
  s[t] = (t < NBK) ? bcnt[t] : 0;
  __syncthreads();
  for (int off = 1; off < 1024; off <<= 1) {
    int v = (t >= off) ? s[t - off] : 0;
    __syncthreads();
    s[t] += v;
    __syncthreads();
  }
  if (t < NBK) {
    int e = (t > 0) ? s[t - 1] : 0;
    bbase[t] = e;
    bcur[t] = e;
  }
  if (t == 0) bbase[NBK] = 2 * NE;
}

__global__ void bucket_scatter(const int* __restrict__ src_g2d, const int* __restrict__ dst_g2d,
                               const int* __restrict__ src_d2g, const int* __restrict__ dst_d2g,
                               int* __restrict__ bcur, int2* __restrict__ pairs) {
  __shared__ int h[NBK];
  __shared__ int base[NBK];
  int e0 = blockIdx.x * EPB;
  int e1 = e0 + EPB;
  if (e1 > 2 * NE) e1 = 2 * NE;
  for (int j = threadIdx.x; j < NBK; j += 256) h[j] = 0;
  __syncthreads();
  for (int i = e0 + threadIdx.x; i < e1; i += 256) {
    int d = (i < NE) ? dst_g2d[i] : ND + dst_d2g[i - NE];
    atomicAdd(&h[d >> 8], 1);
  }
  __syncthreads();
  for (int j = threadIdx.x; j < NBK; j += 256) {
    int c = h[j];
    base[j] = c ? atomicAdd(&bcur[j], c) : 0;
    h[j] = 0;  // reuse as local cursor
  }
  __syncthreads();
  for (int i = e0 + threadIdx.x; i < e1; i += 256) {
    int d, s;
    if (i < NE) {
      d = dst_g2d[i];
      s = src_g2d[i];
    } else {
      d = ND + dst_d2g[i - NE];
      s = src_d2g[i - NE];
    }
    int bkt = d >> 8;
    int p = base[bkt] + atomicAdd(&h[bkt], 1);
    pairs[p] = make_int2(d, s);
  }
}

__global__ void bucket_to_csr(const int* __restrict__ bbase, const int2* __restrict__ pairs,
                              int* __restrict__ off, int* __restrict__ csr) {
  __shared__ int cnt[256];
  __shared__ int ss[256];
  int b = blockIdx.x, t = threadIdx.x;
  int n0 = b << 8;
  int s0 = bbase[b], s1 = bbase[b + 1];
  cnt[t] = 0;
  __syncthreads();
  for (int i = s0 + t; i < s1; i += 256) atomicAdd(&cnt[pairs[i].x - n0], 1);
  __syncthreads();
  int x = cnt[t];
  ss[t] = x;
  __syncthreads();
  for (int o = 1; o < 256; o <<= 1) {
    int y = (t >= o) ? ss[t - o] : 0;
    __syncthreads();
    ss[t] += y;
    __syncthreads();
  }
  int abs0 = s0 + ss[t] - x;
  int node = n0 + t;
  if (node < NTOT) off[node] = abs0;
  if (node == NTOT - 1) off[NTOT] = 2 * NE;
  __syncthreads();
  cnt[t] = abs0;  // absolute cursor
  __syncthreads();
  for (int i = s0 + t; i < s1; i += 256) {
    int2 e = pairs[i];
    int p = atomicAdd(&cnt[e.x - n0], 1);
    csr[p] = e.y;
  }
}

// ---------------- fp32 -> bf16 table convert (RNE), both tables in one launch ------------

__global__ void to_bf16_all(const float* __restrict__ xg, const float* __restrict__ xd,
                            ushort* __restrict__ yg, ushort* __restrict__ yd) {
  int i = blockIdx.x * 256 + threadIdx.x;
  if (i >= NTOT * 16) return;
  const float* x;
  ushort* y;
  int j;
  if (i < NG * 16) {
    x = xg; y = yg; j = i;
  } else {
    x = xd; y = yd; j = i - NG * 16;
  }
  const float4* px = (const float4*)x;
  float4 a = px[2 * j], b = px[2 * j + 1];
  float v[8] = {a.x, a.y, a.z, a.w, b.x, b.y, b.z, b.w};
  uint32 u[4];
#pragma unroll
  for (int k = 0; k < 4; k++)
    u[k] = (uint32)rne_bf16(v[2 * k]) | ((uint32)rne_bf16(v[2 * k + 1]) << 16);
  ((int4*)y)[j] = make_int4((int)u[0], (int)u[1], (int)u[2], (int)u[3]);
}

// ---------------- W pre-split: fp32 -> bf16 hi (trunc) + bf16 lo (residual) --------------

__global__ void split_w(const float* __restrict__ Wl, const float* __restrict__ Wr,
                        ushort* __restrict__ WlH, ushort* __restrict__ WlL,
                        ushort* __restrict__ WrH, ushort* __restrict__ WrL) {
  int i = blockIdx.x * 256 + threadIdx.x;
  if (i >= 4 * 128 * 128) return;
  {
    float a = Wl[i];
    uint32 u = __builtin_bit_cast(uint32, a);
    float hf = __builtin_bit_cast(float, u & 0xffff0000u);
    WlH[i] = (ushort)(u >> 16);
    WlL[i] = (ushort)(__builtin_bit_cast(uint32, a - hf) >> 16);
  }
  {
    float a = Wr[i];
    uint32 u = __builtin_bit_cast(uint32, a);
    float hf = __builtin_bit_cast(float, u & 0xffff0000u);
    WrH[i] = (ushort)(u >> 16);
    WrL[i] = (ushort)(__builtin_bit_cast(uint32, a - hf) >> 16);
  }
}

// ---------------- mean aggregation over bf16 rows, unified node space --------------------
// 16 lanes per node (4 nodes per wave), 4-deep edge unroll: up to 16 gather rows in
// flight per wave (2x the old 64-lane/node layout), no cross-lane reduce needed.

__device__ __forceinline__ void acc8(float* a, int4 u) {
  uint32 w;
  w = (uint32)u.x;
  a[0] += __builtin_bit_cast(float, w << 16);
  a[1] += __builtin_bit_cast(float, w & 0xffff0000u);
  w = (uint32)u.y;
  a[2] += __builtin_bit_cast(float, w << 16);
  a[3] += __builtin_bit_cast(float, w & 0xffff0000u);
  w = (uint32)u.z;
  a[4] += __builtin_bit_cast(float, w << 16);
  a[5] += __builtin_bit_cast(float, w & 0xffff0000u);
  w = (uint32)u.w;
  a[6] += __builtin_bit_cast(float, w << 16);
  a[7] += __builtin_bit_cast(float, w & 0xffff0000u);
}

__global__ void agg_comb(const ushort* __restrict__ xg_bf, const ushort* __restrict__ xd_bf,
                         const int* __restrict__ off, const int* __restrict__ csr,
                         ushort* __restrict__ agg_bf) {
  int node = (blockIdx.x * 256 + threadIdx.x) >> 4;
  if (node >= NTOT) return;
  int l16 = threadIdx.x & 15;
  const int4* xs = (const int4*)((node < ND) ? xg_bf : xd_bf);
  int e0 = off[node], e1 = off[node + 1];
  float a[8] = {0.f, 0.f, 0.f, 0.f, 0.f, 0.f, 0.f, 0.f};
  int e = e0;
  for (; e + 3 < e1; e += 4) {
    int s0 = csr[e], s1 = csr[e + 1], s2 = csr[e + 2], s3 = csr[e + 3];
    int4 v0 = xs[(size_t)s0 * 16 + l16];
    int4 v1 = xs[(size_t)s1 * 16 + l16];
    int4 v2 = xs[(size_t)s2 * 16 + l16];
    int4 v3 = xs[(size_t)s3 * 16 + l16];
    acc8(a, v0);
    acc8(a, v1);
    acc8(a, v2);
    acc8(a, v3);
  }
  for (; e + 1 < e1; e += 2) {
    int s0 = csr[e], s1 = csr[e + 1];
    int4 v0 = xs[(size_t)s0 * 16 + l16];
    int4 v1 = xs[(size_t)s1 * 16 + l16];
    acc8(a, v0);
    acc8(a, v1);
  }
  if (e < e1) acc8(a, xs[(size_t)csr[e] * 16 + l16]);
  int deg = e1 - e0;
  float inv = (deg > 0) ? 1.f / (float)deg : 0.f;
  uint32 u[4];
#pragma unroll
  for (int j = 0; j < 4; j++)
    u[j] = (uint32)rne_bf16(a[2 * j] * inv) | ((uint32)rne_bf16(a[2 * j + 1] * inv) << 16);
  *(int4*)&agg_bf[(size_t)node * DIM + l16 * 8] =
      make_int4((int)u[0], (int)u[1], (int)u[2], (int)u[3]);
}

// ---------------- MFMA SAGE update: per-phase W in LDS (64 KB), 2 blocks/CU --------------
// ph0 needs only Wl hi/lo, ph1 only Wr hi/lo -> stage each pair into the SAME 64 KB
// buffer with a restage barrier between phases. Halving LDS vs R3 doubles resident
// blocks (1 -> 2 per CU), doubling memory-level parallelism for the A/X gathers.
// Main loops stay barrier-free: B from swizzled LDS, A (bf16 int4) and X (fp32,
// hi/lo split in-register) loaded per-lane at MFMA-fragment granularity.

__device__ __forceinline__ void split8(const float* xp, bf16x8& hi, bf16x8& lo) {
  float4 f0 = *(const float4*)xp;
  float4 f1 = *(const float4*)(xp + 4);
  float v[8] = {f0.x, f0.y, f0.z, f0.w, f1.x, f1.y, f1.z, f1.w};
  uint32 hw[4], lw[4];
#pragma unroll
  for (int j = 0; j < 4; j++) {
    uint32 u0 = __builtin_bit_cast(uint32, v[2 * j]);
    uint32 u1 = __builtin_bit_cast(uint32, v[2 * j + 1]);
    float hf0 = __builtin_bit_cast(float, u0 & 0xffff0000u);
    float hf1 = __builtin_bit_cast(float, u1 & 0xffff0000u);
    uint32 l0 = __builtin_bit_cast(uint32, v[2 * j] - hf0) >> 16;
    uint32 l1 = __builtin_bit_cast(uint32, v[2 * j + 1] - hf1) >> 16;
    hw[j] = (u0 >> 16) | ((u1 >> 16) << 16);
    lw[j] = l0 | (l1 << 16);
  }
  hi = __builtin_bit_cast(bf16x8, make_int4((int)hw[0], (int)hw[1], (int)hw[2], (int)hw[3]));
  lo = __builtin_bit_cast(bf16x8, make_int4((int)lw[0], (int)lw[1], (int)lw[2], (int)lw[3]));
}

__launch_bounds__(256, 2)
__global__ void sage_dual(const ushort* __restrict__ agg_bf, const float* __restrict__ xd,
                          const float* __restrict__ xg, const ushort* __restrict__ WlH,
                          const ushort* __restrict__ WlL, const ushort* __restrict__ WrH,
                          const ushort* __restrict__ WrL, const float* __restrict__ bias_all,
                          float* __restrict__ outd, float* __restrict__ outg,
                          ushort* __restrict__ xbf_d, ushort* __restrict__ xbf_g, int layer,
                          int relu, int write_bf) {
  __shared__ __align__(16) char smem[65536];  // [hi 32K][lo 32K] of current phase's W

  int b = blockIdx.x;
  const float* X;
  float* O;
  ushort* OBF;
  int n, set, r0g, cbase;
  if (b < NBT_D2) {
    X = xd; O = outd; OBF = xbf_d; n = ND; set = layer * 2; r0g = b * RPB; cbase = 0;
  } else {
    X = xg; O = outg; OBF = xbf_g; n = NG; set = layer * 2 + 1;
    r0g = (b - NBT_D2) * RPB; cbase = ND;
  }
  const ushort* Wplanes[4] = {WlH + set * 16384, WlL + set * 16384, WrH + set * 16384,
                              WrL + set * 16384};
  const float* bias = bias_all + set * 128;

  int tid = threadIdx.x;
  int wave = tid >> 6, lane = tid & 63;
  int m = lane & 15, q = lane >> 4;

  auto stageW = [&](const ushort* Ph, const ushort* Pl) {
#pragma unroll
    for (int i = 0; i < 16; i++) {
      int c = tid + i * 256;     // 16B chunks; 4096 total (2 planes x 32 KB)
      int p = c >> 11;           // 0 = hi, 1 = lo
      int Bl = (c & 2047) * 16;  // plane-local byte offset (row = Bl>>8)
      const ushort* src = p ? Pl : Ph;
      int4 v = *(const int4*)((const char*)src + Bl);
      int dst = p * 32768 + (Bl ^ (((Bl >> 8) & 7) << 4));
      *(int4*)(smem + dst) = v;
    }
  };

  f32x4 acc[4][8];
#pragma unroll
  for (int mt = 0; mt < 4; mt++)
#pragma unroll
    for (int nt = 0; nt < 8; nt++) acc[mt][nt] = (f32x4)0.f;

  int rb = r0g + wave * 64;

  // ---- ph0: neighbors (bf16 agg rows x (Wl hi + lo) from LDS) ----
  stageW(Wplanes[0], Wplanes[1]);
  __syncthreads();
#pragma unroll
  for (int ks = 0; ks < 4; ks++) {
    int kc = ks * 32 + q * 8;   // ushort col for A
    int kb = ks * 64 + q * 16;  // byte col for W LDS
    bf16x8 a[4];
#pragma unroll
    for (int mt = 0; mt < 4; mt++) {
      int r = rb + mt * 16 + m;
      if (r >= n) r = n - 1;
      a[mt] = __builtin_bit_cast(bf16x8, *(const int4*)&agg_bf[(size_t)(cbase + r) * DIM + kc]);
    }
#pragma unroll
    for (int nt = 0; nt < 8; nt++) {
      int nn = nt * 16 + m;
      int wb = (nn * 256 + kb) ^ ((nn & 7) << 4);
      bf16x8 bh = *(const bf16x8*)(smem + wb);
      bf16x8 bl = *(const bf16x8*)(smem + 32768 + wb);
#pragma unroll
      for (int mt = 0; mt < 4; mt++) {
        acc[mt][nt] = __builtin_amdgcn_mfma_f32_16x16x32_bf16(a[mt], bh, acc[mt][nt], 0, 0, 0);
        acc[mt][nt] = __builtin_amdgcn_mfma_f32_16x16x32_bf16(a[mt], bl, acc[mt][nt], 0, 0, 0);
      }
    }
  }
  __syncthreads();  // done reading Wl planes

  // ---- ph1: root X (fp32 rows split hi/lo in-register x (Wr hi + lo) from LDS) ----
  stageW(Wplanes[2], Wplanes[3]);
  __syncthreads();
#pragma unroll
  for (int ks = 0; ks < 4; ks++) {
    int kc = ks * 32 + q * 8;
    int kb = ks * 64 + q * 16;
    bf16x8 ah[4], al[4];
#pragma unroll
    for (int mt = 0; mt < 4; mt++) {
      int r = rb + mt * 16 + m;
      if (r >= n) r = n - 1;
      split8(&X[(size_t)r * DIM + kc], ah[mt], al[mt]);
    }
#pragma unroll
    for (int nt = 0; nt < 8; nt++) {
      int nn = nt * 16 + m;
      int wb = (nn * 256 + kb) ^ ((nn & 7) << 4);
      bf16x8 bh = *(const bf16x8*)(smem + wb);
      bf16x8 bl = *(const bf16x8*)(smem + 32768 + wb);
#pragma unroll
      for (int mt = 0; mt < 4; mt++) {
        acc[mt][nt] = __builtin_amdgcn_mfma_f32_16x16x32_bf16(ah[mt], bh, acc[mt][nt], 0, 0, 0);
        acc[mt][nt] = __builtin_amdgcn_mfma_f32_16x16x32_bf16(ah[mt], bl, acc[mt][nt], 0, 0, 0);
        acc[mt][nt] = __builtin_amdgcn_mfma_f32_16x16x32_bf16(al[mt], bh, acc[mt][nt], 0, 0, 0);
      }
    }
  }
  __syncthreads();  // all waves done reading W LDS; epilogue aliases it

  // ---- epilogue: bias, relu, L2-normalize, skipsum, store (+ optional bf16 copy) ----
  float bb[8];
#pragma unroll
  for (int nt = 0; nt < 8; nt++) bb[nt] = bias[nt * 16 + m];

  const int S = 132;
  float* wbuf = (float*)smem + wave * (16 * S);  // wave-private: no barriers needed

  int half = lane >> 5;
  int c4 = (lane & 31) * 4;

#pragma unroll
  for (int mt = 0; mt < 4; mt++) {
#pragma unroll
    for (int reg = 0; reg < 4; reg++) {
      float h[8];
      float ss = 0.f;
#pragma unroll
      for (int nt = 0; nt < 8; nt++) {
        float v = acc[mt][nt][reg] + bb[nt];
        if (relu) v = fmaxf(v, 0.f);
        h[nt] = v;
        ss += v * v;
      }
      ss += __shfl_xor(ss, 1);
      ss += __shfl_xor(ss, 2);
      ss += __shfl_xor(ss, 4);
      ss += __shfl_xor(ss, 8);
      float inv = 1.f / fmaxf(sqrtf(ss), EPSN);
      int rrel = q * 4 + reg;
#pragma unroll
      for (int nt = 0; nt < 8; nt++) wbuf[rrel * S + nt * 16 + m] = h[nt] * inv;
    }
#pragma unroll
    for (int i = 0; i < 8; i++) {
      int rrel = i * 2 + half;
      int R = rb + mt * 16 + rrel;
      if (R < n) {
        f32x4 hv = *(const f32x4*)&wbuf[rrel * S + c4];
        float4 xr = *(const float4*)&X[(size_t)R * DIM + c4];
        float4 o;
        o.x = hv[0] + xr.x;
        o.y = hv[1] + xr.y;
        o.z = hv[2] + xr.z;
        o.w = hv[3] + xr.w;
        *(float4*)&O[(size_t)R * DIM + c4] = o;
        if (write_bf) {
          int2 pk = make_int2((int)((uint32)rne_bf16(o.x) | ((uint32)rne_bf16(o.y) << 16)),
                              (int)((uint32)rne_bf16(o.z) | ((uint32)rne_bf16(o.w) << 16)));
          *(int2*)&OBF[(size_t)R * DIM + c4] = pk;
        }
      }
    }
  }
}

// ---------------- launch ----------------

extern "C" void kernel_launch(void* const* d_in, const int* in_sizes, int n_in,
                              void* d_out, int out_size, void* d_ws, size_t ws_size,
                              hipStream_t stream) {
  const float* xg0 = (const float*)d_in[0];
  const float* xd0 = (const float*)d_in[1];
  const float* Wl = (const float*)d_in[2];
  const float* Wr = (const float*)d_in[3];
  const float* bs = (const float*)d_in[4];
  const int* src_g2d = (const int*)d_in[5];
  const int* dst_g2d = (const int*)d_in[6];
  const int* src_d2g = (const int*)d_in[7];
  const int* dst_d2g = (const int*)d_in[8];

  float* out_xg = (float*)d_out;
  float* out_xd = (float*)d_out + (size_t)NG * DIM;

  char* p = (char*)d_ws;
  auto alloc = [&](size_t bytes) -> char* {
    char* q = p;
    p += (bytes + 255) & ~(size_t)255;
    return q;
  };
  int* off = (int*)alloc((NTOT + 1) * 4);
  int* csr = (int*)alloc((size_t)2 * NE * 4);
  int* bcnt = (int*)alloc(NBK * 4);
  int* bbase = (int*)alloc((NBK + 1) * 4);
  int* bcur = (int*)alloc(NBK * 4);
  // pairs (12.8 MB, used only during CSR build) aliases agg_bf (38.4 MB, used after)
  char* big = alloc((size_t)NTOT * DIM * 2);
  int2* pairs = (int2*)big;
  ushort* agg_bf = (ushort*)big;
  ushort* xg_bf = (ushort*)alloc((size_t)NG * DIM * 2);
  ushort* xd_bf = (ushort*)alloc((size_t)ND * DIM * 2);
  ushort* WlH = (ushort*)alloc((size_t)4 * 128 * 128 * 2);
  ushort* WlL = (ushort*)alloc((size_t)4 * 128 * 128 * 2);
  ushort* WrH = (ushort*)alloc((size_t)4 * 128 * 128 * 2);
  ushort* WrL = (ushort*)alloc((size_t)4 * 128 * 128 * 2);

  const int TB = 256;

  split_w<<<256, TB, 0, stream>>>(Wl, Wr, WlH, WlL, WrH, WrL);
  to_bf16_all<<<(NTOT * 16 + TB - 1) / TB, TB, 0, stream>>>(xg0, xd0, xg_bf, xd_bf);

  // bucketed CSR build
  zero_ints<<<(NBK + TB - 1) / TB, TB, 0, stream>>>(bcnt, NBK);
  bucket_count<<<256, TB, 0, stream>>>(dst_g2d, dst_d2g, bcnt);
  bucket_scan<<<1, 1024, 0, stream>>>(bcnt, bbase, bcur);
  bucket_scatter<<<SCB, TB, 0, stream>>>(src_g2d, dst_g2d, src_d2g, dst_d2g, bcur, pairs);
  bucket_to_csr<<<NBK, TB, 0, stream>>>(bbase, pairs, off, csr);

  int aggBlocks = (NTOT * 16 + TB - 1) / TB;  // 9375 (16 lanes per node)
  int sageBlocks = NBT_D2 + NBT_G2;           // 587

  // layer 0 (relu); sage also emits bf16 copy of out for layer-1 gather
  agg_comb<<<aggBlocks, TB, 0, stream>>>(xg_bf, xd_bf, off, csr, agg_bf);
  sage_dual<<<sageBlocks, TB, 0, stream>>>(agg_bf, xd0, xg0, WlH, WlL, WrH, WrL, bs, out_xd,
                                           out_xg, xd_bf, xg_bf, 0, 1, 1);

  // layer 1 (no relu), in-place on d_out
  agg_comb<<<aggBlocks, TB, 0, stream>>>(xg_bf, xd_bf, off, csr, agg_bf);
  sage_dual<<<sageBlocks, TB, 0, stream>>>(agg_bf, out_xd, out_xg, WlH, WlL, WrH, WrL, bs,
                                           out_xd, out_xg, xd_bf, xg_bf, 1, 0, 0);
}